// Round 1
// baseline (197.351 us; speedup 1.0000x reference)
//
#include <hip/hip_runtime.h>

// Problem constants (from reference)
#define KSIZE   32
#define KSTRIDE 16
#define HK      4
#define HD      128
#define ROW     (HK * HD)                       // 512 floats per token
#define BATCH   4
#define SEQLEN  16384
#define CHUNKS_PER_BATCH ((SEQLEN - KSIZE) / KSTRIDE + 1)   // 1023
#define TOTAL_CHUNKS     (BATCH * CHUNKS_PER_BATCH)         // 4092

// One workgroup per chunk. 128 threads; thread t owns float4 slot t of the
// 512-float (4 heads x 128 dim) row. Accumulate 32 consecutive token rows.
__global__ __launch_bounds__(128)
void compress_k_kernel(const float* __restrict__ k,
                       const int* __restrict__ cu_seqlens,
                       float* __restrict__ out) {
    const int chunk = blockIdx.x;
    const int b = chunk / CHUNKS_PER_BATCH;
    const int c = chunk - b * CHUNKS_PER_BATCH;
    const long start_row = (long)cu_seqlens[b] + (long)c * KSTRIDE;

    const float4* __restrict__ src =
        (const float4*)(k + start_row * ROW);
    const int t = threadIdx.x;   // 0..127

    float4 acc = make_float4(0.f, 0.f, 0.f, 0.f);
    #pragma unroll
    for (int i = 0; i < KSIZE; ++i) {
        float4 v = src[(long)i * (ROW / 4) + t];
        acc.x += v.x; acc.y += v.y; acc.z += v.z; acc.w += v.w;
    }
    const float s = 1.0f / (float)KSIZE;
    float4 r = make_float4(acc.x * s, acc.y * s, acc.z * s, acc.w * s);
    ((float4*)(out + (long)chunk * ROW))[t] = r;
}

// Tiny kernel: compute compressed cumulative seqlens and write them as
// float32 into the tail of the output buffer (outputs are concatenated flat).
__global__ void cu_comp_kernel(const int* __restrict__ cu_seqlens,
                               float* __restrict__ tail) {
    if (threadIdx.x == 0 && blockIdx.x == 0) {
        int run = 0;
        tail[0] = 0.0f;
        #pragma unroll
        for (int b = 0; b < BATCH; ++b) {
            const int len = cu_seqlens[b + 1] - cu_seqlens[b];
            const int n = (len >= KSIZE) ? (len - KSIZE) / KSTRIDE + 1 : 0;
            run += n;
            tail[b + 1] = (float)run;
        }
    }
}

extern "C" void kernel_launch(void* const* d_in, const int* in_sizes, int n_in,
                              void* d_out, int out_size, void* d_ws, size_t ws_size,
                              hipStream_t stream) {
    const float* k          = (const float*)d_in[0];
    const int*   cu_seqlens = (const int*)d_in[1];
    float*       out        = (float*)d_out;

    // Output layout: [TOTAL_CHUNKS * ROW floats of compressed_k][BATCH+1 floats cu_comp]
    float* tail = out + (long)TOTAL_CHUNKS * ROW;

    compress_k_kernel<<<TOTAL_CHUNKS, 128, 0, stream>>>(k, cu_seqlens, out);
    cu_comp_kernel<<<1, 64, 0, stream>>>(cu_seqlens, tail);
}

// Round 2
// 194.663 us; speedup vs baseline: 1.0138x; 1.0138x over previous
//
#include <hip/hip_runtime.h>

// Problem constants (from reference)
#define KSIZE   32
#define KSTRIDE 16
#define HK      4
#define HD      128
#define ROW     (HK * HD)                       // 512 floats per token
#define ROW4    (ROW / 4)                       // 128 float4 per token
#define BATCH   4
#define SEQLEN  16384
#define CHUNKS_PER_BATCH ((SEQLEN - KSIZE) / KSTRIDE + 1)   // 1023
#define TOTAL_CHUNKS     (BATCH * CHUNKS_PER_BATCH)         // 4092

// Chunks per block: chunk c = (halfwin c + halfwin c+1)/32, so a block owning
// G consecutive chunks reads (G+1)*16 rows instead of G*32 -> 1.5x less read
// traffic at G=3. 1023 % 3 == 0, so no remainder handling needed.
#define G 3
#define BLOCKS_PER_BATCH (CHUNKS_PER_BATCH / G)             // 341
#define TOTAL_BLOCKS     (BATCH * BLOCKS_PER_BATCH)         // 1364

__global__ __launch_bounds__(128)
void compress_k_fused(const float* __restrict__ k,
                      const int* __restrict__ cu_seqlens,
                      float* __restrict__ out,
                      float* __restrict__ tail) {
    const int blk = blockIdx.x;
    const int b   = blk / BLOCKS_PER_BATCH;
    const int cb  = blk - b * BLOCKS_PER_BATCH;   // block index within batch
    const int c0  = cb * G;                        // first chunk (within batch)

    const long start_row = (long)cu_seqlens[b] + (long)c0 * KSTRIDE;
    const float4* __restrict__ src = (const float4*)(k + start_row * ROW);
    const int t = threadIdx.x;   // 0..127, owns float4 column t

    // G+1 half-window sums (16 rows each), independent accumulation chains.
    float4 h[G + 1];
    #pragma unroll
    for (int j = 0; j <= G; ++j) h[j] = make_float4(0.f, 0.f, 0.f, 0.f);

    #pragma unroll
    for (int j = 0; j <= G; ++j) {
        #pragma unroll
        for (int i = 0; i < KSTRIDE; ++i) {
            float4 v = src[(long)(j * KSTRIDE + i) * ROW4 + t];
            h[j].x += v.x; h[j].y += v.y; h[j].z += v.z; h[j].w += v.w;
        }
    }

    const float s = 1.0f / (float)KSIZE;
    const int chunk0 = b * CHUNKS_PER_BATCH + c0;
    #pragma unroll
    for (int g = 0; g < G; ++g) {
        float4 r = make_float4((h[g].x + h[g + 1].x) * s,
                               (h[g].y + h[g + 1].y) * s,
                               (h[g].z + h[g + 1].z) * s,
                               (h[g].w + h[g + 1].w) * s);
        ((float4*)(out + (long)(chunk0 + g) * ROW))[t] = r;
    }

    // Fused cu_comp tail write (fp32 representation in the flat out buffer).
    if (blk == 0 && t == 0) {
        int run = 0;
        tail[0] = 0.0f;
        #pragma unroll
        for (int i = 0; i < BATCH; ++i) {
            const int len = cu_seqlens[i + 1] - cu_seqlens[i];
            const int n = (len >= KSIZE) ? (len - KSIZE) / KSTRIDE + 1 : 0;
            run += n;
            tail[i + 1] = (float)run;
        }
    }
}

extern "C" void kernel_launch(void* const* d_in, const int* in_sizes, int n_in,
                              void* d_out, int out_size, void* d_ws, size_t ws_size,
                              hipStream_t stream) {
    const float* k          = (const float*)d_in[0];
    const int*   cu_seqlens = (const int*)d_in[1];
    float*       out        = (float*)d_out;
    float*       tail       = out + (long)TOTAL_CHUNKS * ROW;

    compress_k_fused<<<TOTAL_BLOCKS, 128, 0, stream>>>(k, cu_seqlens, out, tail);
}